// Round 4
// baseline (5078.845 us; speedup 1.0000x reference)
//
#include <hip/hip_runtime.h>
#include <math.h>

#define CDIV(a,b) (((a)+(b)-1)/(b))

static constexpr int Cc   = 128;
static constexpr int Hh   = 4;
static constexpr int HCc  = 512;
static constexpr int MIDc = 256;
static constexpr int KS   = 384;   // stacked K for fused edge-score GEMM
static constexpr float INV_SQRT_C = 0.08838834764831845f; // 1/sqrt(128)

typedef __attribute__((ext_vector_type(8))) short bf16x8;
typedef __attribute__((ext_vector_type(4))) float f32x4;

__device__ __forceinline__ unsigned short f2bf(float f) {
    unsigned u = __float_as_uint(f);
    unsigned r = (u + 0x7FFFu + ((u >> 16) & 1u)) >> 16;
    return (unsigned short)r;
}
__device__ __forceinline__ float bf2f(unsigned short v) {
    return __uint_as_float(((unsigned)v) << 16);
}

__device__ __forceinline__ float gelu_tanh(float x) {
    float x3 = x * x * x;
    float t = tanhf(0.7978845608028654f * (x + 0.044715f * x3));
    return 0.5f * x * (1.0f + t);
}

// ---------------- CSR build ----------------
__global__ void k_init_gb(int* gbeg, int* gend, int N, int G) {
    int g = blockIdx.x * blockDim.x + threadIdx.x;
    if (g < G) { gbeg[g] = N; gend[g] = 0; }
}

__global__ void k_node_bounds(const int* __restrict__ batch, int* gbeg, int* gend, int N) {
    int n = blockIdx.x * blockDim.x + threadIdx.x;
    if (n < N) { int b = batch[n]; atomicMin(&gbeg[b], n); atomicMax(&gend[b], n + 1); }
}

__global__ void k_hist(const int* __restrict__ dst, int* __restrict__ cnt, int E) {
    int e = blockIdx.x * blockDim.x + threadIdx.x;
    if (e < E) atomicAdd(&cnt[dst[e]], 1);
}

__global__ void k_scan_blocks(const int* __restrict__ cnt, int* __restrict__ excl,
                              int* __restrict__ partials, int N) {
    __shared__ int buf[1024];
    int tid = threadIdx.x;
    int i = blockIdx.x * 1024 + tid;
    int v = (i < N) ? cnt[i] : 0;
    buf[tid] = v; __syncthreads();
    for (int off = 1; off < 1024; off <<= 1) {
        int t = (tid >= off) ? buf[tid - off] : 0;
        __syncthreads();
        buf[tid] += t;
        __syncthreads();
    }
    if (i < N) excl[i] = buf[tid] - v;
    if (tid == 1023) partials[blockIdx.x] = buf[1023];
}

__global__ void k_scan_partials(int* partials, int P) {
    __shared__ int buf[1024];
    int tid = threadIdx.x;
    int v = (tid < P) ? partials[tid] : 0;
    buf[tid] = v; __syncthreads();
    for (int off = 1; off < 1024; off <<= 1) {
        int t = (tid >= off) ? buf[tid - off] : 0;
        __syncthreads();
        buf[tid] += t;
        __syncthreads();
    }
    if (tid < P) partials[tid] = buf[tid] - v;
}

__global__ void k_scan_add(int* __restrict__ rowoff, const int* __restrict__ partials, int N, int E) {
    int i = blockIdx.x * 1024 + threadIdx.x;
    if (i < N) rowoff[i] += partials[blockIdx.x];
    if (i == 0) rowoff[N] = E;
}

__global__ void k_scatter(const int* __restrict__ src, const int* __restrict__ dst,
                          const int* __restrict__ rowoff, int* __restrict__ cursor,
                          int* __restrict__ srcs, int* __restrict__ dsts,
                          int* __restrict__ eids, int E) {
    int e = blockIdx.x * blockDim.x + threadIdx.x;
    if (e < E) {
        int d = dst[e];
        int p = rowoff[d] + atomicAdd(&cursor[d], 1);
        srcs[p] = src[e];
        dsts[p] = d;
        eids[p] = e;
    }
}

// ---------------- once-per-call conversions ----------------
__global__ void k_conv_ea(const float* __restrict__ edge_attr, const int* __restrict__ eids,
                          unsigned short* __restrict__ eaT, int E) {
    int idx = blockIdx.x * blockDim.x + threadIdx.x;
    if (idx >= E * 32) return;
    int p = idx >> 5, j = idx & 31;
    int eid = eids[p];
    float4 v = *(const float4*)(edge_attr + (size_t)eid * Cc + j * 4);
    unsigned short o[4] = {f2bf(v.x), f2bf(v.y), f2bf(v.z), f2bf(v.w)};
    *(ushort4*)(eaT + (size_t)p * Cc + j * 4) = *(ushort4*)o;
}

// Wt[n][k] = bf16(W[k][n]); layered via blockIdx.y
__global__ void k_w2bf_t(const float* __restrict__ W, unsigned short* __restrict__ Wt,
                         int K, int N, int lgK) {
    int total = K * N;
    const float* Wl = W + (size_t)blockIdx.y * total;
    unsigned short* Wo = Wt + (size_t)blockIdx.y * total;
    int idx = blockIdx.x * blockDim.x + threadIdx.x;
    if (idx >= total) return;
    int k = idx & (K - 1);
    int n = idx >> lgK;
    Wo[idx] = f2bf(Wl[(size_t)k * N + n]);
}

// BtS[l][n][k] (n=512, k=384): k<128 -> We[k][n]; k<256 -> Wl[k-128][n]; else Wr[k-256][n]
__global__ void k_build_bst(const float* __restrict__ We, const float* __restrict__ Wl,
                            const float* __restrict__ Wr, unsigned short* __restrict__ BtS) {
    int l = blockIdx.y;
    int idx = blockIdx.x * blockDim.x + threadIdx.x;
    if (idx >= HCc * KS) return;
    int n = idx / KS, k = idx - n * KS;
    size_t woff = (size_t)l * Cc * HCc;
    float v;
    if (k < 128)      v = We[woff + (size_t)k * HCc + n];
    else if (k < 256) v = Wl[woff + (size_t)(k - 128) * HCc + n];
    else              v = Wr[woff + (size_t)(k - 256) * HCc + n];
    BtS[(size_t)l * HCc * KS + idx] = f2bf(v);
}

// ---------------- mask ----------------
__global__ void k_compute_q(const float* __restrict__ Wm, const float* __restrict__ instr,
                            float* __restrict__ q, int G) {
    int idx = blockIdx.x * blockDim.x + threadIdx.x;
    if (idx >= G * Cc) return;
    int g = idx >> 7, k = idx & 127;
    const float* wrow = Wm + (size_t)k * Cc;
    const float* irow = instr + (size_t)g * Cc;
    float acc = 0.f;
    #pragma unroll 8
    for (int j = 0; j < Cc; ++j) acc += wrow[j] * irow[j];
    q[idx] = acc;
}

__global__ __launch_bounds__(256) void k_mask_xin(const float* __restrict__ h,
                                                  const float* __restrict__ q,
                                                  const int* __restrict__ batch,
                                                  float* __restrict__ maskv,
                                                  unsigned short* __restrict__ x_in, int N) {
    int wid = (blockIdx.x * blockDim.x + threadIdx.x) >> 6;
    if (wid >= N) return;
    int lane = threadIdx.x & 63;
    int b = batch[wid];
    float2 hv = ((const float2*)(h + (size_t)wid * Cc))[lane];
    float2 qv = ((const float2*)(q + (size_t)b * Cc))[lane];
    float part = hv.x * qv.x + hv.y * qv.y;
    #pragma unroll
    for (int off = 1; off < 64; off <<= 1) part += __shfl_xor(part, off);
    float m = 1.0f / (1.0f + expf(-part * INV_SQRT_C));
    if (lane == 0) maskv[wid] = m;
    unsigned short o[2] = {f2bf(m * hv.x), f2bf(m * hv.y)};
    *(ushort2*)(x_in + (size_t)wid * Cc + lane * 2) = *(ushort2*)o;
}

__global__ __launch_bounds__(256) void k_sdot(const float* __restrict__ cr,
                                              const float* __restrict__ instr,
                                              const int* __restrict__ batch,
                                              float* __restrict__ sarr, int N) {
    int wid = (blockIdx.x * blockDim.x + threadIdx.x) >> 6;
    if (wid >= N) return;
    int lane = threadIdx.x & 63;
    int b = batch[wid];
    float2 cv = ((const float2*)(cr + (size_t)wid * Cc))[lane];
    float2 iv = ((const float2*)(instr + (size_t)b * Cc))[lane];
    float part = cv.x * iv.x + cv.y * iv.y;
    #pragma unroll
    for (int off = 1; off < 64; off <<= 1) part += __shfl_xor(part, off);
    if (lane == 0) sarr[wid] = part * INV_SQRT_C;
}

// ---------------- generic bf16 MFMA GEMM ----------------
__global__ __launch_bounds__(256) void k_gemm_bf16(const unsigned short* __restrict__ A,
                                                   const unsigned short* __restrict__ Bt,
                                                   const float* __restrict__ bias,
                                                   float* __restrict__ outF,
                                                   unsigned short* __restrict__ outB,
                                                   int M, int K, int N, int act) {
    int wave = threadIdx.x >> 6, lane = threadIdx.x & 63;
    int q = lane >> 4, l15 = lane & 15;
    int waves_per_n = N >> 7;
    int rows_per_block = (waves_per_n == 4) ? 32 : (waves_per_n == 2) ? 64 : 128;
    int wrow = (waves_per_n == 4) ? 0 : (waves_per_n == 2) ? (wave >> 1) : wave;
    int wcol = wave & (waves_per_n - 1);
    int r0 = blockIdx.x * rows_per_block + wrow * 32;
    int cb = wcol << 7;

    int ra = r0 + l15;        if (ra >= M) ra = M - 1;
    int rb = r0 + 16 + l15;   if (rb >= M) rb = M - 1;
    const unsigned short* Apa = A + (size_t)ra * K + q * 8;
    const unsigned short* Apb = A + (size_t)rb * K + q * 8;

    f32x4 acc[2][8] = {};
    for (int k0 = 0; k0 < K; k0 += 32) {
        bf16x8 a0 = *(const bf16x8*)(Apa + k0);
        bf16x8 a1 = *(const bf16x8*)(Apb + k0);
        #pragma unroll
        for (int t = 0; t < 8; ++t) {
            int n = cb + t * 16 + l15;
            bf16x8 b = *(const bf16x8*)(Bt + (size_t)n * K + k0 + q * 8);
            acc[0][t] = __builtin_amdgcn_mfma_f32_16x16x32_bf16(a0, b, acc[0][t], 0, 0, 0);
            acc[1][t] = __builtin_amdgcn_mfma_f32_16x16x32_bf16(a1, b, acc[1][t], 0, 0, 0);
        }
    }
    #pragma unroll
    for (int s = 0; s < 2; ++s) {
        #pragma unroll
        for (int t = 0; t < 8; ++t) {
            int n = cb + t * 16 + l15;
            float bv = bias ? bias[n] : 0.f;
            #pragma unroll
            for (int r = 0; r < 4; ++r) {
                int m = r0 + s * 16 + q * 4 + r;
                if (m < M) {
                    float v = acc[s][t][r] + bv;
                    if (act) v = gelu_tanh(v);
                    if (outF) outF[(size_t)m * N + n] = v;
                    if (outB) outB[(size_t)m * N + n] = f2bf(v);
                }
            }
        }
    }
}

// ---------------- fused edge-score GEMM, K=384 stacked ----------------
// score[p][h] = sum_n lrelu( ([ea[p];x_in[src];x_in[dst]] @ [We;Wl;Wr])[n] ) * att[n]
// Block = 32 CSR edges x 4 waves (wave = head). NO epilogue gathers.
__global__ __launch_bounds__(256) void k_edge_scores_fused(const unsigned short* __restrict__ eaT,
                                                           const unsigned short* __restrict__ x_in,
                                                           const unsigned short* __restrict__ BtS,
                                                           const int* __restrict__ srcs,
                                                           const int* __restrict__ dsts,
                                                           const float* __restrict__ att,
                                                           float* __restrict__ scores, int E) {
    int wave = threadIdx.x >> 6, lane = threadIdx.x & 63;
    int q = lane >> 4, l15 = lane & 15;
    int p0 = blockIdx.x * 32;
    __shared__ int s_src[32], s_dst[32];
    if (threadIdx.x < 32) {
        int p = p0 + threadIdx.x;
        int pc = (p < E) ? p : E - 1;
        s_src[threadIdx.x] = srcs[pc];
        s_dst[threadIdx.x] = dsts[pc];
    }
    __syncthreads();

    int h = wave;
    int cbh = h << 7;
    int eA = p0 + l15;      if (eA >= E) eA = E - 1;
    int eB = p0 + 16 + l15; if (eB >= E) eB = E - 1;
    const unsigned short* a_ea[2] = { eaT + (size_t)eA * Cc + q * 8,
                                      eaT + (size_t)eB * Cc + q * 8 };
    const unsigned short* a_xs[2] = { x_in + (size_t)s_src[l15] * Cc + q * 8,
                                      x_in + (size_t)s_src[16 + l15] * Cc + q * 8 };
    const unsigned short* a_xd[2] = { x_in + (size_t)s_dst[l15] * Cc + q * 8,
                                      x_in + (size_t)s_dst[16 + l15] * Cc + q * 8 };

    f32x4 acc[2][8] = {};
    #pragma unroll
    for (int c = 0; c < 12; ++c) {
        int k0 = c << 5;
        int koff = (c & 3) << 5;
        bf16x8 a0, a1;
        if (c < 4)      { a0 = *(const bf16x8*)(a_ea[0] + koff); a1 = *(const bf16x8*)(a_ea[1] + koff); }
        else if (c < 8) { a0 = *(const bf16x8*)(a_xs[0] + koff); a1 = *(const bf16x8*)(a_xs[1] + koff); }
        else            { a0 = *(const bf16x8*)(a_xd[0] + koff); a1 = *(const bf16x8*)(a_xd[1] + koff); }
        #pragma unroll
        for (int t = 0; t < 8; ++t) {
            int n = cbh + t * 16 + l15;
            bf16x8 b = *(const bf16x8*)(BtS + (size_t)n * KS + k0 + q * 8);
            acc[0][t] = __builtin_amdgcn_mfma_f32_16x16x32_bf16(a0, b, acc[0][t], 0, 0, 0);
            acc[1][t] = __builtin_amdgcn_mfma_f32_16x16x32_bf16(a1, b, acc[1][t], 0, 0, 0);
        }
    }

    float sc[2][4] = {{0.f,0.f,0.f,0.f},{0.f,0.f,0.f,0.f}};
    #pragma unroll
    for (int t = 0; t < 8; ++t) {
        int n = cbh + t * 16 + l15;
        float attn = att[n];
        #pragma unroll
        for (int s = 0; s < 2; ++s) {
            #pragma unroll
            for (int r = 0; r < 4; ++r) {
                float v = acc[s][t][r];
                v = (v > 0.f) ? v : 0.2f * v;
                sc[s][r] += v * attn;
            }
        }
    }
    #pragma unroll
    for (int s = 0; s < 2; ++s) {
        #pragma unroll
        for (int r = 0; r < 4; ++r) {
            float v = sc[s][r];
            v += __shfl_xor(v, 1);
            v += __shfl_xor(v, 2);
            v += __shfl_xor(v, 4);
            v += __shfl_xor(v, 8);
            if (l15 == 0) {
                int p = p0 + s * 16 + q * 4 + r;
                if (p < E) scores[(size_t)p * 4 + h] = v;
            }
        }
    }
}

// ---------------- online-softmax aggregation (one wave per dst node) ----------------
__global__ __launch_bounds__(256) void k_edge_agg(const unsigned short* __restrict__ xlB,
                                                  const float* __restrict__ scores,
                                                  const int* __restrict__ rowoff,
                                                  const int* __restrict__ srcs,
                                                  unsigned short* __restrict__ out, int N) {
    int wid = (blockIdx.x * blockDim.x + threadIdx.x) >> 6;
    if (wid >= N) return;
    int lane = threadIdx.x & 63;
    int cbase = lane << 3;
    int h = lane >> 4;

    float m_run = -INFINITY, s_run = 0.f;
    float acc[8] = {0.f, 0.f, 0.f, 0.f, 0.f, 0.f, 0.f, 0.f};

    int p0 = rowoff[wid], p1 = rowoff[wid + 1];
    for (int p = p0; p < p1; ++p) {
        int s = srcs[p];
        float sc_e = scores[(size_t)p * 4 + h];
        ushort4 u0 = *(const ushort4*)(xlB + (size_t)s * HCc + cbase);
        ushort4 u1 = *(const ushort4*)(xlB + (size_t)s * HCc + cbase + 4);
        float xlv[8] = {bf2f(u0.x), bf2f(u0.y), bf2f(u0.z), bf2f(u0.w),
                        bf2f(u1.x), bf2f(u1.y), bf2f(u1.z), bf2f(u1.w)};
        float mn = fmaxf(m_run, sc_e);
        float rescale = expf(m_run - mn);
        float w = expf(sc_e - mn);
        s_run = s_run * rescale + w;
        #pragma unroll
        for (int j = 0; j < 8; ++j) acc[j] = acc[j] * rescale + w * xlv[j];
        m_run = mn;
    }
    float inv = 1.0f / (s_run + 1e-16f);
    unsigned short o[8];
    #pragma unroll
    for (int j = 0; j < 8; ++j) o[j] = f2bf(acc[j] * inv);
    *(bf16x8*)(out + (size_t)wid * HCc + cbase) = *(bf16x8*)o;
}

// ---------------- per-graph node softmax ----------------
__global__ void k_graph_softmax(const float* __restrict__ s, const int* __restrict__ gbeg,
                                const int* __restrict__ gend, float* __restrict__ a) {
    int g = blockIdx.x;
    int n0 = gbeg[g], n1 = gend[g];
    __shared__ float red[256];
    int tid = threadIdx.x;
    float lm = -INFINITY;
    for (int n = n0 + tid; n < n1; n += 256) lm = fmaxf(lm, s[n]);
    red[tid] = lm; __syncthreads();
    for (int off = 128; off > 0; off >>= 1) {
        if (tid < off) red[tid] = fmaxf(red[tid], red[tid + off]);
        __syncthreads();
    }
    float mx = red[0]; __syncthreads();
    float ls = 0.f;
    for (int n = n0 + tid; n < n1; n += 256) ls += expf(s[n] - mx);
    red[tid] = ls; __syncthreads();
    for (int off = 128; off > 0; off >>= 1) {
        if (tid < off) red[tid] += red[tid + off];
        __syncthreads();
    }
    float inv = 1.0f / (red[0] + 1e-16f);
    for (int n = n0 + tid; n < n1; n += 256) a[n] = expf(s[n] - mx) * inv;
}

// ---------------- GraphNorm stats ----------------
__global__ __launch_bounds__(512) void k_gn_stats(const float* __restrict__ cr,
                                                  const float* __restrict__ a,
                                                  const int* __restrict__ gbeg,
                                                  const int* __restrict__ gend,
                                                  const float* __restrict__ alpha,
                                                  float* __restrict__ meanb,
                                                  float* __restrict__ varb) {
    int g = blockIdx.x;
    int n0 = gbeg[g], n1 = gend[g];
    int c = threadIdx.x & 127;
    int sub = threadIdx.x >> 7;
    __shared__ float red[4][128];
    float accv = 0.f;
    for (int n = n0 + sub; n < n1; n += 4) accv += a[n] * cr[(size_t)n * Cc + c];
    red[sub][c] = accv; __syncthreads();
    float cntf = (n1 > n0) ? (float)(n1 - n0) : 0.f;
    float invc = 1.0f / fmaxf(cntf, 1.0f);
    if (sub == 0) {
        float m = (red[0][c] + red[1][c] + red[2][c] + red[3][c]) * invc;
        meanb[g * Cc + c] = m;
        red[0][c] = m;
    }
    __syncthreads();
    float mean = red[0][c];
    __syncthreads();
    float am = alpha[c] * mean;
    float acc2 = 0.f;
    for (int n = n0 + sub; n < n1; n += 4) {
        float v = a[n] * cr[(size_t)n * Cc + c] - am;
        acc2 += v * v;
    }
    red[sub][c] = acc2; __syncthreads();
    if (sub == 0) varb[g * Cc + c] = (red[0][c] + red[1][c] + red[2][c] + red[3][c]) * invc;
}

// ---------------- final elementwise ----------------
__global__ void k_final(const float* __restrict__ cr, const float* __restrict__ a,
                        const float* __restrict__ h, const float* __restrict__ maskv,
                        const int* __restrict__ batch, const float* __restrict__ meanb,
                        const float* __restrict__ varb, const float* __restrict__ gamma,
                        const float* __restrict__ beta, const float* __restrict__ alpha,
                        float* __restrict__ hout, int N) {
    int idx = blockIdx.x * blockDim.x + threadIdx.x;
    if (idx >= N * Cc) return;
    int n = idx >> 7, c = idx & 127;
    int g = batch[n];
    float acr = a[n] * cr[idx];
    float sb = acr - alpha[c] * meanb[g * Cc + c];
    float crn = gamma[c] * sb / sqrtf(varb[g * Cc + c] + 1e-5f) + beta[c];
    hout[idx] = maskv[n] * (crn + h[idx]);
}

// ---------------- launch ----------------
extern "C" void kernel_launch(void* const* d_in, const int* in_sizes, int n_in,
                              void* d_out, int out_size, void* d_ws, size_t ws_size,
                              hipStream_t stream) {
    const float* x         = (const float*)d_in[0];
    const int*   edge_idx  = (const int*)d_in[1];
    const float* instr     = (const float*)d_in[2];
    const float* edge_attr = (const float*)d_in[4];
    const int*   batch     = (const int*)d_in[5];
    const float* Wl        = (const float*)d_in[6];
    const float* Wr        = (const float*)d_in[7];
    const float* We        = (const float*)d_in[8];
    const float* att       = (const float*)d_in[9];
    const float* Wm        = (const float*)d_in[10];
    const float* p1_w      = (const float*)d_in[11];
    const float* p1_b      = (const float*)d_in[12];
    const float* p2_w      = (const float*)d_in[13];
    const float* p2_b      = (const float*)d_in[14];
    const float* gn_gamma  = (const float*)d_in[15];
    const float* gn_beta   = (const float*)d_in[16];
    const float* gn_alpha  = (const float*)d_in[17];

    const int N = in_sizes[0] / Cc;
    const int E = in_sizes[4] / Cc;
    const int G = in_sizes[3] / Cc;
    const int L = in_sizes[6] / (Cc * HCc);
    (void)n_in; (void)ws_size; (void)out_size;

    const int* e_src = edge_idx;
    const int* e_dst = edge_idx + E;

    char* pw = (char*)d_ws;
    auto alloc = [&](size_t bytes) -> void* {
        void* r = (void*)pw;
        pw += (bytes + 255) & ~(size_t)255;
        return r;
    };
    // ~300 MB arena
    float* h_buf            = (float*)alloc((size_t)N * Cc * 4);          // 25.6 MB
    void*  xin_cr_region    = alloc((size_t)N * Cc * 4);                  // 25.6 MB
    unsigned short* xlB     = (unsigned short*)alloc((size_t)N * HCc * 2);// 51.2 MB
    unsigned short* aggB    = (unsigned short*)alloc((size_t)N * HCc * 2);// 51.2 MB
    unsigned short* mid     = (unsigned short*)alloc((size_t)N * MIDc * 2);// 25.6 MB
    unsigned short* eaT     = (unsigned short*)alloc((size_t)E * Cc * 2); // 102.4 MB
    float* scores           = (float*)alloc((size_t)E * 4 * 4);           // 6.4 MB
    unsigned short* WlT     = (unsigned short*)alloc((size_t)L * Cc * HCc * 2);
    unsigned short* BtS     = (unsigned short*)alloc((size_t)L * HCc * KS * 2);
    unsigned short* p1T     = (unsigned short*)alloc((size_t)L * HCc * MIDc * 2);
    unsigned short* p2T     = (unsigned short*)alloc((size_t)L * MIDc * Cc * 2);
    float* maskv  = (float*)alloc((size_t)N * 4);
    float* sarr   = (float*)alloc((size_t)N * 4);
    float* aarr   = (float*)alloc((size_t)N * 4);
    float* qbuf   = (float*)alloc((size_t)G * Cc * 4);
    float* meanb  = (float*)alloc((size_t)G * Cc * 4);
    float* varb   = (float*)alloc((size_t)G * Cc * 4);
    int* rowoff   = (int*)alloc(((size_t)N + 1) * 4);
    int* cnt      = (int*)alloc((size_t)N * 4);
    int* cursor   = (int*)alloc((size_t)N * 4);
    int* gbeg     = (int*)alloc((size_t)G * 4);
    int* gend     = (int*)alloc((size_t)G * 4);
    int* partials = (int*)alloc(1024 * 4);
    int* srcs     = (int*)alloc((size_t)E * 4);
    int* dsts     = (int*)alloc((size_t)E * 4);
    int* eids     = (int*)alloc((size_t)E * 4);
    unsigned short* x_in = (unsigned short*)xin_cr_region; // live: mask_xin .. edge_scores
    float* cr            = (float*)xin_cr_region;          // live: p2 gemm .. k_final

    // init h = x
    hipMemcpyAsync(h_buf, x, (size_t)N * Cc * 4, hipMemcpyDeviceToDevice, stream);

    // graph node ranges
    k_init_gb<<<CDIV(G, 64), 64, 0, stream>>>(gbeg, gend, N, G);
    k_node_bounds<<<CDIV(N, 256), 256, 0, stream>>>(batch, gbeg, gend, N);

    // CSR by dst
    hipMemsetAsync(cnt, 0, (size_t)N * 4, stream);
    hipMemsetAsync(cursor, 0, (size_t)N * 4, stream);
    k_hist<<<CDIV(E, 256), 256, 0, stream>>>(e_dst, cnt, E);
    int nb = CDIV(N, 1024);
    k_scan_blocks<<<nb, 1024, 0, stream>>>(cnt, rowoff, partials, N);
    k_scan_partials<<<1, 1024, 0, stream>>>(partials, nb);
    k_scan_add<<<nb, 1024, 0, stream>>>(rowoff, partials, N, E);
    k_scatter<<<CDIV(E, 256), 256, 0, stream>>>(e_src, e_dst, rowoff, cursor, srcs, dsts, eids, E);

    // once-per-call conversions
    k_conv_ea<<<CDIV(E * 32, 256), 256, 0, stream>>>(edge_attr, eids, eaT, E);
    {
        dim3 g1(CDIV(Cc * HCc, 256), L);
        k_w2bf_t<<<g1, 256, 0, stream>>>(Wl, WlT, Cc, HCc, 7);
        dim3 gs(CDIV(HCc * KS, 256), L);
        k_build_bst<<<gs, 256, 0, stream>>>(We, Wl, Wr, BtS);
        dim3 g2(CDIV(HCc * MIDc, 256), L);
        k_w2bf_t<<<g2, 256, 0, stream>>>(p1_w, p1T, HCc, MIDc, 9);
        dim3 g3(CDIV(MIDc * Cc, 256), L);
        k_w2bf_t<<<g3, 256, 0, stream>>>(p2_w, p2T, MIDc, Cc, 8);
    }

    for (int i = 0; i < L; ++i) {
        const float* Wm_i    = Wm + (size_t)i * Cc * Cc;
        const float* instr_i = instr + (size_t)i * G * Cc;
        const unsigned short* WlT_i = WlT + (size_t)i * Cc * HCc;
        const unsigned short* BtS_i = BtS + (size_t)i * HCc * KS;
        const unsigned short* p1T_i = p1T + (size_t)i * HCc * MIDc;
        const unsigned short* p2T_i = p2T + (size_t)i * MIDc * Cc;
        const float* att_i   = att + (size_t)i * Hh * Cc;
        const float* p1b_i   = p1_b + (size_t)i * MIDc;
        const float* p2b_i   = p2_b + (size_t)i * Cc;
        const float* gam_i   = gn_gamma + (size_t)i * Cc;
        const float* bet_i   = gn_beta + (size_t)i * Cc;
        const float* alp_i   = gn_alpha + (size_t)i * Cc;

        // mask + x_in (bf16)
        k_compute_q<<<CDIV(G * Cc, 256), 256, 0, stream>>>(Wm_i, instr_i, qbuf, G);
        k_mask_xin<<<CDIV(N, 4), 256, 0, stream>>>(h_buf, qbuf, batch, maskv, x_in, N);

        // xl (bf16 out) — only needed for aggregation
        k_gemm_bf16<<<CDIV(N, 32), 256, 0, stream>>>(x_in, WlT_i, nullptr, nullptr, xlB, N, Cc, HCc, 0);

        // fused edge scores (K=384 stacked GEMM, no epilogue gathers) + aggregation
        k_edge_scores_fused<<<CDIV(E, 32), 256, 0, stream>>>(eaT, x_in, BtS_i, srcs, dsts,
                                                             att_i, scores, E);
        k_edge_agg<<<CDIV(N, 4), 256, 0, stream>>>(xlB, scores, rowoff, srcs, aggB, N);

        // MLP (bf16 chain, fp32 out at cr)
        k_gemm_bf16<<<CDIV(N, 64), 256, 0, stream>>>(aggB, p1T_i, p1b_i, nullptr, mid, N, HCc, MIDc, 1);
        k_gemm_bf16<<<CDIV(N, 128), 256, 0, stream>>>(mid, p2T_i, p2b_i, cr, nullptr, N, MIDc, Cc, 1);

        // per-graph scatter attention softmax
        k_sdot<<<CDIV(N, 4), 256, 0, stream>>>(cr, instr_i, batch, sarr, N);
        k_graph_softmax<<<G, 256, 0, stream>>>(sarr, gbeg, gend, aarr);

        // GraphNorm stats
        k_gn_stats<<<G, 512, 0, stream>>>(cr, aarr, gbeg, gend, alp_i, meanb, varb);

        // final elementwise: h = mask*(norm(cr) + h)
        float* hout = (i == L - 1) ? (float*)d_out : h_buf;
        k_final<<<CDIV(N * Cc, 256), 256, 0, stream>>>(cr, aarr, h_buf, maskv, batch, meanb,
                                                       varb, gam_i, bet_i, alp_i, hout, N);
    }
}

// Round 5
// 4059.246 us; speedup vs baseline: 1.2512x; 1.2512x over previous
//
#include <hip/hip_runtime.h>
#include <math.h>

#define CDIV(a,b) (((a)+(b)-1)/(b))

static constexpr int Cc   = 128;
static constexpr int Hh   = 4;
static constexpr int HCc  = 512;
static constexpr int MIDc = 256;
static constexpr int KS   = 384;   // stacked K for fused edge-score GEMM
static constexpr float INV_SQRT_C = 0.08838834764831845f; // 1/sqrt(128)

typedef __attribute__((ext_vector_type(8))) short bf16x8;
typedef __attribute__((ext_vector_type(4))) float f32x4;

__device__ __forceinline__ unsigned short f2bf(float f) {
    unsigned u = __float_as_uint(f);
    unsigned r = (u + 0x7FFFu + ((u >> 16) & 1u)) >> 16;
    return (unsigned short)r;
}
__device__ __forceinline__ float bf2f(unsigned short v) {
    return __uint_as_float(((unsigned)v) << 16);
}

__device__ __forceinline__ float gelu_tanh(float x) {
    float x3 = x * x * x;
    float t = tanhf(0.7978845608028654f * (x + 0.044715f * x3));
    return 0.5f * x * (1.0f + t);
}

// ---------------- CSR build ----------------
__global__ void k_init_gb(int* gbeg, int* gend, int N, int G) {
    int g = blockIdx.x * blockDim.x + threadIdx.x;
    if (g < G) { gbeg[g] = N; gend[g] = 0; }
}

__global__ void k_node_bounds(const int* __restrict__ batch, int* gbeg, int* gend, int N) {
    int n = blockIdx.x * blockDim.x + threadIdx.x;
    if (n < N) { int b = batch[n]; atomicMin(&gbeg[b], n); atomicMax(&gend[b], n + 1); }
}

__global__ void k_hist(const int* __restrict__ dst, int* __restrict__ cnt, int E) {
    int e = blockIdx.x * blockDim.x + threadIdx.x;
    if (e < E) atomicAdd(&cnt[dst[e]], 1);
}

__global__ void k_scan_blocks(const int* __restrict__ cnt, int* __restrict__ excl,
                              int* __restrict__ partials, int N) {
    __shared__ int buf[1024];
    int tid = threadIdx.x;
    int i = blockIdx.x * 1024 + tid;
    int v = (i < N) ? cnt[i] : 0;
    buf[tid] = v; __syncthreads();
    for (int off = 1; off < 1024; off <<= 1) {
        int t = (tid >= off) ? buf[tid - off] : 0;
        __syncthreads();
        buf[tid] += t;
        __syncthreads();
    }
    if (i < N) excl[i] = buf[tid] - v;
    if (tid == 1023) partials[blockIdx.x] = buf[1023];
}

__global__ void k_scan_partials(int* partials, int P) {
    __shared__ int buf[1024];
    int tid = threadIdx.x;
    int v = (tid < P) ? partials[tid] : 0;
    buf[tid] = v; __syncthreads();
    for (int off = 1; off < 1024; off <<= 1) {
        int t = (tid >= off) ? buf[tid - off] : 0;
        __syncthreads();
        buf[tid] += t;
        __syncthreads();
    }
    if (tid < P) partials[tid] = buf[tid] - v;
}

__global__ void k_scan_add(int* __restrict__ rowoff, const int* __restrict__ partials, int N, int E) {
    int i = blockIdx.x * 1024 + threadIdx.x;
    if (i < N) rowoff[i] += partials[blockIdx.x];
    if (i == 0) rowoff[N] = E;
}

__global__ void k_scatter(const int* __restrict__ src, const int* __restrict__ dst,
                          const int* __restrict__ rowoff, int* __restrict__ cursor,
                          int* __restrict__ srcs, int* __restrict__ dsts,
                          int* __restrict__ eids, int E) {
    int e = blockIdx.x * blockDim.x + threadIdx.x;
    if (e < E) {
        int d = dst[e];
        int p = rowoff[d] + atomicAdd(&cursor[d], 1);
        srcs[p] = src[e];
        dsts[p] = d;
        eids[p] = e;
    }
}

// ---------------- once-per-call conversions ----------------
__global__ void k_conv_ea(const float* __restrict__ edge_attr, const int* __restrict__ eids,
                          unsigned short* __restrict__ eaT, int E) {
    int idx = blockIdx.x * blockDim.x + threadIdx.x;
    if (idx >= E * 32) return;
    int p = idx >> 5, j = idx & 31;
    int eid = eids[p];
    float4 v = *(const float4*)(edge_attr + (size_t)eid * Cc + j * 4);
    unsigned short o[4] = {f2bf(v.x), f2bf(v.y), f2bf(v.z), f2bf(v.w)};
    *(ushort4*)(eaT + (size_t)p * Cc + j * 4) = *(ushort4*)o;
}

// Wt[n][k] = bf16(W[k][n]); layered via blockIdx.y
__global__ void k_w2bf_t(const float* __restrict__ W, unsigned short* __restrict__ Wt,
                         int K, int N, int lgK) {
    int total = K * N;
    const float* Wl = W + (size_t)blockIdx.y * total;
    unsigned short* Wo = Wt + (size_t)blockIdx.y * total;
    int idx = blockIdx.x * blockDim.x + threadIdx.x;
    if (idx >= total) return;
    int k = idx & (K - 1);
    int n = idx >> lgK;
    Wo[idx] = f2bf(Wl[(size_t)k * N + n]);
}

// BtS[l][n][k] (n=512, k=384): k<128 -> We[k][n]; k<256 -> Wl[k-128][n]; else Wr[k-256][n]
__global__ void k_build_bst(const float* __restrict__ We, const float* __restrict__ Wl,
                            const float* __restrict__ Wr, unsigned short* __restrict__ BtS) {
    int l = blockIdx.y;
    int idx = blockIdx.x * blockDim.x + threadIdx.x;
    if (idx >= HCc * KS) return;
    int n = idx / KS, k = idx - n * KS;
    size_t woff = (size_t)l * Cc * HCc;
    float v;
    if (k < 128)      v = We[woff + (size_t)k * HCc + n];
    else if (k < 256) v = Wl[woff + (size_t)(k - 128) * HCc + n];
    else              v = Wr[woff + (size_t)(k - 256) * HCc + n];
    BtS[(size_t)l * HCc * KS + idx] = f2bf(v);
}

// ---------------- mask ----------------
__global__ void k_compute_q(const float* __restrict__ Wm, const float* __restrict__ instr,
                            float* __restrict__ q, int G) {
    int idx = blockIdx.x * blockDim.x + threadIdx.x;
    if (idx >= G * Cc) return;
    int g = idx >> 7, k = idx & 127;
    const float* wrow = Wm + (size_t)k * Cc;
    const float* irow = instr + (size_t)g * Cc;
    float acc = 0.f;
    #pragma unroll 8
    for (int j = 0; j < Cc; ++j) acc += wrow[j] * irow[j];
    q[idx] = acc;
}

__global__ __launch_bounds__(256) void k_mask_xin(const float* __restrict__ h,
                                                  const float* __restrict__ q,
                                                  const int* __restrict__ batch,
                                                  float* __restrict__ maskv,
                                                  unsigned short* __restrict__ x_in, int N) {
    int wid = (blockIdx.x * blockDim.x + threadIdx.x) >> 6;
    if (wid >= N) return;
    int lane = threadIdx.x & 63;
    int b = batch[wid];
    float2 hv = ((const float2*)(h + (size_t)wid * Cc))[lane];
    float2 qv = ((const float2*)(q + (size_t)b * Cc))[lane];
    float part = hv.x * qv.x + hv.y * qv.y;
    #pragma unroll
    for (int off = 1; off < 64; off <<= 1) part += __shfl_xor(part, off);
    float m = 1.0f / (1.0f + expf(-part * INV_SQRT_C));
    if (lane == 0) maskv[wid] = m;
    unsigned short o[2] = {f2bf(m * hv.x), f2bf(m * hv.y)};
    *(ushort2*)(x_in + (size_t)wid * Cc + lane * 2) = *(ushort2*)o;
}

__global__ __launch_bounds__(256) void k_sdot(const float* __restrict__ cr,
                                              const float* __restrict__ instr,
                                              const int* __restrict__ batch,
                                              float* __restrict__ sarr, int N) {
    int wid = (blockIdx.x * blockDim.x + threadIdx.x) >> 6;
    if (wid >= N) return;
    int lane = threadIdx.x & 63;
    int b = batch[wid];
    float2 cv = ((const float2*)(cr + (size_t)wid * Cc))[lane];
    float2 iv = ((const float2*)(instr + (size_t)b * Cc))[lane];
    float part = cv.x * iv.x + cv.y * iv.y;
    #pragma unroll
    for (int off = 1; off < 64; off <<= 1) part += __shfl_xor(part, off);
    if (lane == 0) sarr[wid] = part * INV_SQRT_C;
}

// ---------------- generic bf16 MFMA GEMM ----------------
__global__ __launch_bounds__(256) void k_gemm_bf16(const unsigned short* __restrict__ A,
                                                   const unsigned short* __restrict__ Bt,
                                                   const float* __restrict__ bias,
                                                   float* __restrict__ outF,
                                                   unsigned short* __restrict__ outB,
                                                   int M, int K, int N, int act) {
    int wave = threadIdx.x >> 6, lane = threadIdx.x & 63;
    int q = lane >> 4, l15 = lane & 15;
    int waves_per_n = N >> 7;
    int rows_per_block = (waves_per_n == 4) ? 32 : (waves_per_n == 2) ? 64 : 128;
    int wrow = (waves_per_n == 4) ? 0 : (waves_per_n == 2) ? (wave >> 1) : wave;
    int wcol = wave & (waves_per_n - 1);
    int r0 = blockIdx.x * rows_per_block + wrow * 32;
    int cb = wcol << 7;

    int ra = r0 + l15;        if (ra >= M) ra = M - 1;
    int rb = r0 + 16 + l15;   if (rb >= M) rb = M - 1;
    const unsigned short* Apa = A + (size_t)ra * K + q * 8;
    const unsigned short* Apb = A + (size_t)rb * K + q * 8;

    f32x4 acc[2][8] = {};
    for (int k0 = 0; k0 < K; k0 += 32) {
        bf16x8 a0 = *(const bf16x8*)(Apa + k0);
        bf16x8 a1 = *(const bf16x8*)(Apb + k0);
        #pragma unroll
        for (int t = 0; t < 8; ++t) {
            int n = cb + t * 16 + l15;
            bf16x8 b = *(const bf16x8*)(Bt + (size_t)n * K + k0 + q * 8);
            acc[0][t] = __builtin_amdgcn_mfma_f32_16x16x32_bf16(a0, b, acc[0][t], 0, 0, 0);
            acc[1][t] = __builtin_amdgcn_mfma_f32_16x16x32_bf16(a1, b, acc[1][t], 0, 0, 0);
        }
    }
    #pragma unroll
    for (int s = 0; s < 2; ++s) {
        #pragma unroll
        for (int t = 0; t < 8; ++t) {
            int n = cb + t * 16 + l15;
            float bv = bias ? bias[n] : 0.f;
            #pragma unroll
            for (int r = 0; r < 4; ++r) {
                int m = r0 + s * 16 + q * 4 + r;
                if (m < M) {
                    float v = acc[s][t][r] + bv;
                    if (act) v = gelu_tanh(v);
                    if (outF) outF[(size_t)m * N + n] = v;
                    if (outB) outB[(size_t)m * N + n] = f2bf(v);
                }
            }
        }
    }
}

// ---------------- fused edge-score GEMM, K=384 stacked, M=64/wave ----------------
// score[p][h] = sum_n lrelu( ([ea[p];x_in[src];x_in[dst]] @ [We;Wl;Wr])[n] ) * att[n]
// Block = 64 CSR edges x 4 waves (wave = head). 4 row-subtiles per wave: 12 loads
// feed 32 MFMAs per K-chunk; 12-chunk loop fully unrolled for SW pipelining.
__global__ __launch_bounds__(256, 2) void k_edge_scores_fused(const unsigned short* __restrict__ eaT,
                                                              const unsigned short* __restrict__ x_in,
                                                              const unsigned short* __restrict__ BtS,
                                                              const int* __restrict__ srcs,
                                                              const int* __restrict__ dsts,
                                                              const float* __restrict__ att,
                                                              float* __restrict__ scores, int E) {
    int wave = threadIdx.x >> 6, lane = threadIdx.x & 63;
    int q = lane >> 4, l15 = lane & 15;
    int p0 = blockIdx.x * 64;
    __shared__ int s_src[64], s_dst[64];
    if (threadIdx.x < 64) {
        int p = p0 + threadIdx.x;
        int pc = (p < E) ? p : E - 1;
        s_src[threadIdx.x] = srcs[pc];
        s_dst[threadIdx.x] = dsts[pc];
    }
    __syncthreads();

    int h = wave;
    int cbh = h << 7;
    const unsigned short* a_ea[4];
    const unsigned short* a_xs[4];
    const unsigned short* a_xd[4];
    #pragma unroll
    for (int st = 0; st < 4; ++st) {
        int e = p0 + st * 16 + l15; if (e >= E) e = E - 1;
        a_ea[st] = eaT + (size_t)e * Cc + q * 8;
        a_xs[st] = x_in + (size_t)s_src[st * 16 + l15] * Cc + q * 8;
        a_xd[st] = x_in + (size_t)s_dst[st * 16 + l15] * Cc + q * 8;
    }

    f32x4 acc[4][8] = {};
    #pragma unroll
    for (int c = 0; c < 12; ++c) {
        int k0 = c << 5;
        int koff = (c & 3) << 5;
        bf16x8 a[4];
        #pragma unroll
        for (int st = 0; st < 4; ++st) {
            const unsigned short* p = (c < 4) ? a_ea[st] : (c < 8) ? a_xs[st] : a_xd[st];
            a[st] = *(const bf16x8*)(p + koff);
        }
        #pragma unroll
        for (int t = 0; t < 8; ++t) {
            int n = cbh + t * 16 + l15;
            bf16x8 b = *(const bf16x8*)(BtS + (size_t)n * KS + k0 + q * 8);
            #pragma unroll
            for (int st = 0; st < 4; ++st)
                acc[st][t] = __builtin_amdgcn_mfma_f32_16x16x32_bf16(a[st], b, acc[st][t], 0, 0, 0);
        }
    }

    float sc[4][4] = {};
    #pragma unroll
    for (int t = 0; t < 8; ++t) {
        int n = cbh + t * 16 + l15;
        float attn = att[n];
        #pragma unroll
        for (int st = 0; st < 4; ++st) {
            #pragma unroll
            for (int r = 0; r < 4; ++r) {
                float v = acc[st][t][r];
                v = (v > 0.f) ? v : 0.2f * v;
                sc[st][r] += v * attn;
            }
        }
    }
    #pragma unroll
    for (int st = 0; st < 4; ++st) {
        #pragma unroll
        for (int r = 0; r < 4; ++r) {
            float v = sc[st][r];
            v += __shfl_xor(v, 1);
            v += __shfl_xor(v, 2);
            v += __shfl_xor(v, 4);
            v += __shfl_xor(v, 8);
            if (l15 == 0) {
                int p = p0 + st * 16 + q * 4 + r;
                if (p < E) scores[(size_t)p * 4 + h] = v;
            }
        }
    }
}

// ---------------- online-softmax aggregation (one wave per dst node) ----------------
__global__ __launch_bounds__(256) void k_edge_agg(const unsigned short* __restrict__ xlB,
                                                  const float* __restrict__ scores,
                                                  const int* __restrict__ rowoff,
                                                  const int* __restrict__ srcs,
                                                  unsigned short* __restrict__ out, int N) {
    int wid = (blockIdx.x * blockDim.x + threadIdx.x) >> 6;
    if (wid >= N) return;
    int lane = threadIdx.x & 63;
    int cbase = lane << 3;
    int h = lane >> 4;

    float m_run = -INFINITY, s_run = 0.f;
    float acc[8] = {0.f, 0.f, 0.f, 0.f, 0.f, 0.f, 0.f, 0.f};

    int p0 = rowoff[wid], p1 = rowoff[wid + 1];
    for (int p = p0; p < p1; ++p) {
        int s = srcs[p];
        float sc_e = scores[(size_t)p * 4 + h];
        ushort4 u0 = *(const ushort4*)(xlB + (size_t)s * HCc + cbase);
        ushort4 u1 = *(const ushort4*)(xlB + (size_t)s * HCc + cbase + 4);
        float xlv[8] = {bf2f(u0.x), bf2f(u0.y), bf2f(u0.z), bf2f(u0.w),
                        bf2f(u1.x), bf2f(u1.y), bf2f(u1.z), bf2f(u1.w)};
        float mn = fmaxf(m_run, sc_e);
        float rescale = expf(m_run - mn);
        float w = expf(sc_e - mn);
        s_run = s_run * rescale + w;
        #pragma unroll
        for (int j = 0; j < 8; ++j) acc[j] = acc[j] * rescale + w * xlv[j];
        m_run = mn;
    }
    float inv = 1.0f / (s_run + 1e-16f);
    unsigned short o[8];
    #pragma unroll
    for (int j = 0; j < 8; ++j) o[j] = f2bf(acc[j] * inv);
    *(bf16x8*)(out + (size_t)wid * HCc + cbase) = *(bf16x8*)o;
}

// ---------------- per-graph node softmax ----------------
__global__ void k_graph_softmax(const float* __restrict__ s, const int* __restrict__ gbeg,
                                const int* __restrict__ gend, float* __restrict__ a) {
    int g = blockIdx.x;
    int n0 = gbeg[g], n1 = gend[g];
    __shared__ float red[256];
    int tid = threadIdx.x;
    float lm = -INFINITY;
    for (int n = n0 + tid; n < n1; n += 256) lm = fmaxf(lm, s[n]);
    red[tid] = lm; __syncthreads();
    for (int off = 128; off > 0; off >>= 1) {
        if (tid < off) red[tid] = fmaxf(red[tid], red[tid + off]);
        __syncthreads();
    }
    float mx = red[0]; __syncthreads();
    float ls = 0.f;
    for (int n = n0 + tid; n < n1; n += 256) ls += expf(s[n] - mx);
    red[tid] = ls; __syncthreads();
    for (int off = 128; off > 0; off >>= 1) {
        if (tid < off) red[tid] += red[tid + off];
        __syncthreads();
    }
    float inv = 1.0f / (red[0] + 1e-16f);
    for (int n = n0 + tid; n < n1; n += 256) a[n] = expf(s[n] - mx) * inv;
}

// ---------------- GraphNorm stats ----------------
__global__ __launch_bounds__(512) void k_gn_stats(const float* __restrict__ cr,
                                                  const float* __restrict__ a,
                                                  const int* __restrict__ gbeg,
                                                  const int* __restrict__ gend,
                                                  const float* __restrict__ alpha,
                                                  float* __restrict__ meanb,
                                                  float* __restrict__ varb) {
    int g = blockIdx.x;
    int n0 = gbeg[g], n1 = gend[g];
    int c = threadIdx.x & 127;
    int sub = threadIdx.x >> 7;
    __shared__ float red[4][128];
    float accv = 0.f;
    for (int n = n0 + sub; n < n1; n += 4) accv += a[n] * cr[(size_t)n * Cc + c];
    red[sub][c] = accv; __syncthreads();
    float cntf = (n1 > n0) ? (float)(n1 - n0) : 0.f;
    float invc = 1.0f / fmaxf(cntf, 1.0f);
    if (sub == 0) {
        float m = (red[0][c] + red[1][c] + red[2][c] + red[3][c]) * invc;
        meanb[g * Cc + c] = m;
        red[0][c] = m;
    }
    __syncthreads();
    float mean = red[0][c];
    __syncthreads();
    float am = alpha[c] * mean;
    float acc2 = 0.f;
    for (int n = n0 + sub; n < n1; n += 4) {
        float v = a[n] * cr[(size_t)n * Cc + c] - am;
        acc2 += v * v;
    }
    red[sub][c] = acc2; __syncthreads();
    if (sub == 0) varb[g * Cc + c] = (red[0][c] + red[1][c] + red[2][c] + red[3][c]) * invc;
}

// ---------------- final elementwise ----------------
__global__ void k_final(const float* __restrict__ cr, const float* __restrict__ a,
                        const float* __restrict__ h, const float* __restrict__ maskv,
                        const int* __restrict__ batch, const float* __restrict__ meanb,
                        const float* __restrict__ varb, const float* __restrict__ gamma,
                        const float* __restrict__ beta, const float* __restrict__ alpha,
                        float* __restrict__ hout, int N) {
    int idx = blockIdx.x * blockDim.x + threadIdx.x;
    if (idx >= N * Cc) return;
    int n = idx >> 7, c = idx & 127;
    int g = batch[n];
    float acr = a[n] * cr[idx];
    float sb = acr - alpha[c] * meanb[g * Cc + c];
    float crn = gamma[c] * sb / sqrtf(varb[g * Cc + c] + 1e-5f) + beta[c];
    hout[idx] = maskv[n] * (crn + h[idx]);
}

// ---------------- launch ----------------
extern "C" void kernel_launch(void* const* d_in, const int* in_sizes, int n_in,
                              void* d_out, int out_size, void* d_ws, size_t ws_size,
                              hipStream_t stream) {
    const float* x         = (const float*)d_in[0];
    const int*   edge_idx  = (const int*)d_in[1];
    const float* instr     = (const float*)d_in[2];
    const float* edge_attr = (const float*)d_in[4];
    const int*   batch     = (const int*)d_in[5];
    const float* Wl        = (const float*)d_in[6];
    const float* Wr        = (const float*)d_in[7];
    const float* We        = (const float*)d_in[8];
    const float* att       = (const float*)d_in[9];
    const float* Wm        = (const float*)d_in[10];
    const float* p1_w      = (const float*)d_in[11];
    const float* p1_b      = (const float*)d_in[12];
    const float* p2_w      = (const float*)d_in[13];
    const float* p2_b      = (const float*)d_in[14];
    const float* gn_gamma  = (const float*)d_in[15];
    const float* gn_beta   = (const float*)d_in[16];
    const float* gn_alpha  = (const float*)d_in[17];

    const int N = in_sizes[0] / Cc;
    const int E = in_sizes[4] / Cc;
    const int G = in_sizes[3] / Cc;
    const int L = in_sizes[6] / (Cc * HCc);
    (void)n_in; (void)ws_size; (void)out_size;

    const int* e_src = edge_idx;
    const int* e_dst = edge_idx + E;

    char* pw = (char*)d_ws;
    auto alloc = [&](size_t bytes) -> void* {
        void* r = (void*)pw;
        pw += (bytes + 255) & ~(size_t)255;
        return r;
    };
    // ~300 MB arena
    float* h_buf            = (float*)alloc((size_t)N * Cc * 4);          // 25.6 MB
    void*  xin_cr_region    = alloc((size_t)N * Cc * 4);                  // 25.6 MB
    unsigned short* xlB     = (unsigned short*)alloc((size_t)N * HCc * 2);// 51.2 MB
    unsigned short* aggB    = (unsigned short*)alloc((size_t)N * HCc * 2);// 51.2 MB
    unsigned short* mid     = (unsigned short*)alloc((size_t)N * MIDc * 2);// 25.6 MB
    unsigned short* eaT     = (unsigned short*)alloc((size_t)E * Cc * 2); // 102.4 MB
    float* scores           = (float*)alloc((size_t)E * 4 * 4);           // 6.4 MB
    unsigned short* WlT     = (unsigned short*)alloc((size_t)L * Cc * HCc * 2);
    unsigned short* BtS     = (unsigned short*)alloc((size_t)L * HCc * KS * 2);
    unsigned short* p1T     = (unsigned short*)alloc((size_t)L * HCc * MIDc * 2);
    unsigned short* p2T     = (unsigned short*)alloc((size_t)L * MIDc * Cc * 2);
    float* maskv  = (float*)alloc((size_t)N * 4);
    float* sarr   = (float*)alloc((size_t)N * 4);
    float* aarr   = (float*)alloc((size_t)N * 4);
    float* qbuf   = (float*)alloc((size_t)G * Cc * 4);
    float* meanb  = (float*)alloc((size_t)G * Cc * 4);
    float* varb   = (float*)alloc((size_t)G * Cc * 4);
    int* rowoff   = (int*)alloc(((size_t)N + 1) * 4);
    int* cnt      = (int*)alloc((size_t)N * 4);
    int* cursor   = (int*)alloc((size_t)N * 4);
    int* gbeg     = (int*)alloc((size_t)G * 4);
    int* gend     = (int*)alloc((size_t)G * 4);
    int* partials = (int*)alloc(1024 * 4);
    int* srcs     = (int*)alloc((size_t)E * 4);
    int* dsts     = (int*)alloc((size_t)E * 4);
    int* eids     = (int*)alloc((size_t)E * 4);
    unsigned short* x_in = (unsigned short*)xin_cr_region; // live: mask_xin .. edge_scores
    float* cr            = (float*)xin_cr_region;          // live: p2 gemm .. k_final

    // init h = x
    hipMemcpyAsync(h_buf, x, (size_t)N * Cc * 4, hipMemcpyDeviceToDevice, stream);

    // graph node ranges
    k_init_gb<<<CDIV(G, 64), 64, 0, stream>>>(gbeg, gend, N, G);
    k_node_bounds<<<CDIV(N, 256), 256, 0, stream>>>(batch, gbeg, gend, N);

    // CSR by dst
    hipMemsetAsync(cnt, 0, (size_t)N * 4, stream);
    hipMemsetAsync(cursor, 0, (size_t)N * 4, stream);
    k_hist<<<CDIV(E, 256), 256, 0, stream>>>(e_dst, cnt, E);
    int nb = CDIV(N, 1024);
    k_scan_blocks<<<nb, 1024, 0, stream>>>(cnt, rowoff, partials, N);
    k_scan_partials<<<1, 1024, 0, stream>>>(partials, nb);
    k_scan_add<<<nb, 1024, 0, stream>>>(rowoff, partials, N, E);
    k_scatter<<<CDIV(E, 256), 256, 0, stream>>>(e_src, e_dst, rowoff, cursor, srcs, dsts, eids, E);

    // once-per-call conversions
    k_conv_ea<<<CDIV(E * 32, 256), 256, 0, stream>>>(edge_attr, eids, eaT, E);
    {
        dim3 g1(CDIV(Cc * HCc, 256), L);
        k_w2bf_t<<<g1, 256, 0, stream>>>(Wl, WlT, Cc, HCc, 7);
        dim3 gs(CDIV(HCc * KS, 256), L);
        k_build_bst<<<gs, 256, 0, stream>>>(We, Wl, Wr, BtS);
        dim3 g2(CDIV(HCc * MIDc, 256), L);
        k_w2bf_t<<<g2, 256, 0, stream>>>(p1_w, p1T, HCc, MIDc, 9);
        dim3 g3(CDIV(MIDc * Cc, 256), L);
        k_w2bf_t<<<g3, 256, 0, stream>>>(p2_w, p2T, MIDc, Cc, 8);
    }

    for (int i = 0; i < L; ++i) {
        const float* Wm_i    = Wm + (size_t)i * Cc * Cc;
        const float* instr_i = instr + (size_t)i * G * Cc;
        const unsigned short* WlT_i = WlT + (size_t)i * Cc * HCc;
        const unsigned short* BtS_i = BtS + (size_t)i * HCc * KS;
        const unsigned short* p1T_i = p1T + (size_t)i * HCc * MIDc;
        const unsigned short* p2T_i = p2T + (size_t)i * MIDc * Cc;
        const float* att_i   = att + (size_t)i * Hh * Cc;
        const float* p1b_i   = p1_b + (size_t)i * MIDc;
        const float* p2b_i   = p2_b + (size_t)i * Cc;
        const float* gam_i   = gn_gamma + (size_t)i * Cc;
        const float* bet_i   = gn_beta + (size_t)i * Cc;
        const float* alp_i   = gn_alpha + (size_t)i * Cc;

        // mask + x_in (bf16)
        k_compute_q<<<CDIV(G * Cc, 256), 256, 0, stream>>>(Wm_i, instr_i, qbuf, G);
        k_mask_xin<<<CDIV(N, 4), 256, 0, stream>>>(h_buf, qbuf, batch, maskv, x_in, N);

        // xl (bf16 out) — only needed for aggregation
        k_gemm_bf16<<<CDIV(N, 32), 256, 0, stream>>>(x_in, WlT_i, nullptr, nullptr, xlB, N, Cc, HCc, 0);

        // fused edge scores (K=384 stacked GEMM, M=64/wave) + aggregation
        k_edge_scores_fused<<<CDIV(E, 64), 256, 0, stream>>>(eaT, x_in, BtS_i, srcs, dsts,
                                                             att_i, scores, E);
        k_edge_agg<<<CDIV(N, 4), 256, 0, stream>>>(xlB, scores, rowoff, srcs, aggB, N);

        // MLP (bf16 chain, fp32 out at cr)
        k_gemm_bf16<<<CDIV(N, 64), 256, 0, stream>>>(aggB, p1T_i, p1b_i, nullptr, mid, N, HCc, MIDc, 1);
        k_gemm_bf16<<<CDIV(N, 128), 256, 0, stream>>>(mid, p2T_i, p2b_i, cr, nullptr, N, MIDc, Cc, 1);

        // per-graph scatter attention softmax
        k_sdot<<<CDIV(N, 4), 256, 0, stream>>>(cr, instr_i, batch, sarr, N);
        k_graph_softmax<<<G, 256, 0, stream>>>(sarr, gbeg, gend, aarr);

        // GraphNorm stats
        k_gn_stats<<<G, 512, 0, stream>>>(cr, aarr, gbeg, gend, alp_i, meanb, varb);

        // final elementwise: h = mask*(norm(cr) + h)
        float* hout = (i == L - 1) ? (float*)d_out : h_buf;
        k_final<<<CDIV(N * Cc, 256), 256, 0, stream>>>(cr, aarr, h_buf, maskv, batch, meanb,
                                                       varb, gam_i, bet_i, alp_i, hout, N);
    }
}